// Round 8
// baseline (632.944 us; speedup 1.0000x reference)
//
#include <hip/hip_runtime.h>
#include <math.h>

#define N_NODES 50000
#define N_EDGES 800000
#define DIM 128
#define SCAN_BLOCKS 49      // 49*1024 = 50176 >= 50001

typedef __attribute__((ext_vector_type(8))) short short8;
typedef __attribute__((ext_vector_type(4))) float floatx4;

// f32 -> bf16 bits, round-to-nearest-even (matches v_cvt / numpy)
__device__ __forceinline__ unsigned short f32_to_bf16(float f) {
    unsigned int u = __float_as_uint(f);
    u += 0x7fffu + ((u >> 16) & 1u);
    return (unsigned short)(u >> 16);
}
__device__ __forceinline__ float bf16_to_f32(unsigned short h) {
    return __uint_as_float((unsigned int)h << 16);
}

// ---------------- CSR build ----------------

__global__ __launch_bounds__(256) void hist_kernel(const int* __restrict__ dst,
                                                   int* __restrict__ deg) {
    int e = blockIdx.x * 256 + threadIdx.x;
    if (e < N_EDGES) atomicAdd(&deg[dst[e]], 1);
}

__global__ __launch_bounds__(1024) void scan1(const int* __restrict__ deg,
                                              int* __restrict__ rowp,
                                              int* __restrict__ part) {
    __shared__ int buf[1024];
    int i = blockIdx.x * 1024 + threadIdx.x;
    int v = (i < N_NODES) ? deg[i] : 0;
    buf[threadIdx.x] = v;
    __syncthreads();
    for (int off = 1; off < 1024; off <<= 1) {
        int t = (threadIdx.x >= (unsigned)off) ? buf[threadIdx.x - off] : 0;
        __syncthreads();
        buf[threadIdx.x] += t;
        __syncthreads();
    }
    if (i < N_NODES) rowp[i] = buf[threadIdx.x] - v;   // local exclusive
    if (threadIdx.x == 1023) part[blockIdx.x] = buf[1023];
}

__global__ void scan2(int* __restrict__ part) {        // 1 block, 64 threads
    int v = (threadIdx.x < SCAN_BLOCKS) ? part[threadIdx.x] : 0;
    for (int off = 1; off < 64; off <<= 1) {
        int t = __shfl_up(v, off);
        if ((int)threadIdx.x >= off) v += t;
    }
    if (threadIdx.x < SCAN_BLOCKS) part[threadIdx.x] = v;   // inclusive totals
}

__global__ __launch_bounds__(1024) void scan3(int* __restrict__ rowp,
                                              int* __restrict__ cursor,
                                              const int* __restrict__ part) {
    int i = blockIdx.x * 1024 + threadIdx.x;
    int off = (blockIdx.x > 0) ? part[blockIdx.x - 1] : 0;
    if (i < N_NODES) {
        int r = rowp[i] + off;
        rowp[i] = r;
        cursor[i] = r;
    }
    if (i == N_NODES) rowp[N_NODES] = part[SCAN_BLOCKS - 1];  // == N_EDGES
}

// pass 1: only a 4B perm write per edge (halves write-amplified dirty lines)
__global__ __launch_bounds__(256) void scatter_perm(const int* __restrict__ dst,
                                                    int* __restrict__ cursor,
                                                    int* __restrict__ perm) {
    int e = blockIdx.x * 256 + threadIdx.x;
    if (e < N_EDGES) {
        int pos = atomicAdd(&cursor[dst[e]], 1);
        perm[pos] = e;
    }
}

// pass 2: random READS (L3-dedup'd across XCDs), coalesced writes
__global__ __launch_bounds__(256) void build_ep(const int* __restrict__ perm,
                                                const int* __restrict__ src,
                                                const float* __restrict__ ew,
                                                int2* __restrict__ ep) {
    int s = blockIdx.x * 256 + threadIdx.x;
    if (s < N_EDGES) {
        int e = perm[s];
        int2 p; p.x = src[e]; p.y = __float_as_int(ew[e]);
        ep[s] = p;
    }
}

// ---------------- fused SpMM + residual mix (wave-per-node) -----------------
// One 64-lane wave per node: lane = (edge-group eg 0..3, feature-octet 0..15).
// One wave-inst gathers 4 edges' full 256B rows (16 lines) — no intra-wave
// max-deg divergence, 4x the occupancy of the 4-lane/node version.

__global__ __launch_bounds__(256) void spmm6(const unsigned short* __restrict__ hB,
                                             const unsigned short* __restrict__ x0B,
                                             const int* __restrict__ rowp,
                                             const int2* __restrict__ ep,
                                             unsigned short* __restrict__ mB) {
    int node = blockIdx.x * 4 + (threadIdx.x >> 6);   // 4 waves/block, 50000=12500*4
    int lane = threadIdx.x & 63;
    int eg = lane >> 4;                               // edge group 0..3
    int fb = (lane & 15) * 8;                         // feature octet
    int beg = rowp[node], end = rowp[node + 1];
    float acc[8] = {0.f, 0.f, 0.f, 0.f, 0.f, 0.f, 0.f, 0.f};
    if (beg < end) {
        for (int i = beg; i < end; i += 4) {
            int idx = i + eg;
            int2 e = ep[min(idx, end - 1)];
            float w = (idx < end) ? __int_as_float(e.y) : 0.f;
            short8 r = *(const short8*)(const void*)(hB + (size_t)e.x * DIM + fb);
#pragma unroll
            for (int j = 0; j < 8; j++)
                acc[j] = fmaf(w, bf16_to_f32((unsigned short)r[j]), acc[j]);
        }
    }
    // reduce the 4 edge groups into lanes 0..15
#pragma unroll
    for (int j = 0; j < 8; j++) {
        acc[j] += __shfl_down(acc[j], 32);
        acc[j] += __shfl_down(acc[j], 16);
    }
    if (lane < 16) {
        size_t off = (size_t)node * DIM + fb;
        short8 xv = *(const short8*)(const void*)(x0B + off);
        short8 o;
#pragma unroll
        for (int j = 0; j < 8; j++)
            o[j] = (short)f32_to_bf16(0.9f * acc[j]
                                      + 0.1f * bf16_to_f32((unsigned short)xv[j]));
        *(short8*)(void*)(mB + off) = o;
    }
}

// ---------------- MFMA GEMM: out = relu(A @ (cg*W + cm*I) + bias) -----------
// Residual FOLDED into the weight during LDS staging: W'[k][n] = cg*W + cm*I.
// A: [N,128] row-major, f32 (AF32=true) or bf16. outF f32 / outB bf16 optional.

template <bool AF32>
__global__ __launch_bounds__(256) void gemm128(const void* __restrict__ Av,
                                               const float* __restrict__ W,
                                               const float* __restrict__ bias,
                                               float* __restrict__ outF,
                                               unsigned short* __restrict__ outB,
                                               float cm, float cg) {
    __shared__ unsigned short WT[128][136];   // transposed, +8 pad
    for (int idx = threadIdx.x; idx < 128 * 128; idx += 256) {
        int k = idx >> 7, n = idx & 127;
        float wv = cg * W[idx] + ((n == k) ? cm : 0.f);
        WT[n][k] = f32_to_bf16(wv);
    }
    __syncthreads();

    int wave = threadIdx.x >> 6;
    int lane = threadIdx.x & 63;
    int r0 = (blockIdx.x * 4 + wave) * 16;
    if (r0 >= N_NODES) return;                 // 16 | 50000, full tiles only

    int mrow = lane & 15;                      // A row within tile; also C col
    int quad = lane >> 4;

    floatx4 acc[8];
#pragma unroll
    for (int t = 0; t < 8; t++) acc[t] = {0.f, 0.f, 0.f, 0.f};

#pragma unroll
    for (int k0 = 0; k0 < 128; k0 += 32) {
        short8 a;
        if constexpr (AF32) {
            const float* arow = (const float*)Av + (size_t)(r0 + mrow) * DIM;
            floatx4 alo = *(const floatx4*)(const void*)(arow + k0 + quad * 8);
            floatx4 ahi = *(const floatx4*)(const void*)(arow + k0 + quad * 8 + 4);
#pragma unroll
            for (int j = 0; j < 4; j++) a[j] = (short)f32_to_bf16(alo[j]);
#pragma unroll
            for (int j = 0; j < 4; j++) a[4 + j] = (short)f32_to_bf16(ahi[j]);
        } else {
            const unsigned short* arow = (const unsigned short*)Av + (size_t)(r0 + mrow) * DIM;
            a = *(const short8*)(const void*)(arow + k0 + quad * 8);
        }
#pragma unroll
        for (int t = 0; t < 8; t++) {
            short8 b = *(const short8*)(const void*)(&WT[t * 16 + mrow][k0 + quad * 8]);
            acc[t] = __builtin_amdgcn_mfma_f32_16x16x32_bf16(a, b, acc[t], 0, 0, 0);
        }
    }

    // C/D layout: col = lane&15, row = quad*4 + i  [verified m89/m91]
#pragma unroll
    for (int t = 0; t < 8; t++) {
        int col = t * 16 + mrow;
        float bv = bias ? bias[col] : 0.f;
#pragma unroll
        for (int i = 0; i < 4; i++) {
            int row = r0 + quad * 4 + i;
            size_t off = (size_t)row * DIM + col;
            float v = fmaxf(acc[t][i] + bv, 0.f);
            if (outF) outF[off] = v;
            if (outB) outB[off] = f32_to_bf16(v);
        }
    }
}

// ---------------- launch ----------------

extern "C" void kernel_launch(void* const* d_in, const int* in_sizes, int n_in,
                              void* d_out, int out_size, void* d_ws, size_t ws_size,
                              hipStream_t stream) {
    const float* x    = (const float*)d_in[0];
    const float* ew   = (const float*)d_in[1];
    const float* Wlin = (const float*)d_in[2];
    const float* blin = (const float*)d_in[3];
    const float* Wcv  = (const float*)d_in[4];
    const int* eidx = (const int*)d_in[5];
    const int* esrc = eidx;
    const int* edst = eidx + N_EDGES;
    float* out = (float*)d_out;

    char* ws = (char*)d_ws;
    unsigned short* x0B = (unsigned short*)(ws);             // 12.8 MB bf16 x0 rows
    unsigned short* mB  = (unsigned short*)(ws + 12800000);  // 12.8 MB bf16 m rows
    unsigned short* hB  = (unsigned short*)(ws + 25600000);  // 12.8 MB bf16 h rows
    int* rowp           = (int*)(ws + 38400000);             // (N+1)*4
    int* cursor         = (int*)(ws + 38600064);             // also 'deg'
    int2* epack         = (int2*)(ws + 38800128);            // E*8
    int* perm           = (int*)(ws + 45200128);             // E*4
    int* part           = (int*)(ws + 48400128);             // scan partials
    // total ~48.4 MB

    // CSR build (every call; no static state)
    (void)hipMemsetAsync(cursor, 0, (N_NODES + 1) * sizeof(int), stream);
    hist_kernel<<<(N_EDGES + 255) / 256, 256, 0, stream>>>(edst, cursor);
    scan1<<<SCAN_BLOCKS, 1024, 0, stream>>>(cursor, rowp, part);
    scan2<<<1, 64, 0, stream>>>(part);
    scan3<<<SCAN_BLOCKS, 1024, 0, stream>>>(rowp, cursor, part);
    scatter_perm<<<(N_EDGES + 255) / 256, 256, 0, stream>>>(edst, cursor, perm);
    build_ep<<<(N_EDGES + 255) / 256, 256, 0, stream>>>(perm, esrc, ew, epack);

    const int grid = (N_NODES + 63) / 64;   // 782

    // x0 = relu(x @ W_lin + b_lin) -> bf16 rows
    gemm128<true><<<grid, 256, 0, stream>>>(x, Wlin, blin, nullptr, x0B, 0.f, 1.f);

    const unsigned short* hin = x0B;
    for (int l = 0; l < 8; l++) {
        spmm6<<<N_NODES / 4, 256, 0, stream>>>(hin, x0B, rowp, epack, mB);
        float beta = logf(0.5f / (float)(l + 1) + 1.f);
        gemm128<false><<<grid, 256, 0, stream>>>(mB, Wcv + (size_t)l * DIM * DIM, nullptr,
                                                 (l == 7) ? out : nullptr,
                                                 (l < 7) ? hB : nullptr,
                                                 1.f - beta, beta);
        hin = hB;
    }
}

// Round 9
// 550.338 us; speedup vs baseline: 1.1501x; 1.1501x over previous
//
#include <hip/hip_runtime.h>
#include <math.h>

#define N_NODES 50000
#define N_EDGES 800000
#define DIM 128
#define SCAN_BLOCKS 49      // 49*1024 = 50176 >= 50001

typedef __attribute__((ext_vector_type(8))) short short8;
typedef __attribute__((ext_vector_type(4))) float floatx4;

// f32 -> bf16 bits, round-to-nearest-even (matches v_cvt / numpy)
__device__ __forceinline__ unsigned short f32_to_bf16(float f) {
    unsigned int u = __float_as_uint(f);
    u += 0x7fffu + ((u >> 16) & 1u);
    return (unsigned short)(u >> 16);
}
__device__ __forceinline__ float bf16_to_f32(unsigned short h) {
    return __uint_as_float((unsigned int)h << 16);
}

// ---------------- CSR build ----------------

__global__ __launch_bounds__(256) void hist_kernel(const int* __restrict__ dst,
                                                   int* __restrict__ deg) {
    int e = blockIdx.x * 256 + threadIdx.x;
    if (e < N_EDGES) atomicAdd(&deg[dst[e]], 1);
}

__global__ __launch_bounds__(1024) void scan1(const int* __restrict__ deg,
                                              int* __restrict__ rowp,
                                              int* __restrict__ part) {
    __shared__ int buf[1024];
    int i = blockIdx.x * 1024 + threadIdx.x;
    int v = (i < N_NODES) ? deg[i] : 0;
    buf[threadIdx.x] = v;
    __syncthreads();
    for (int off = 1; off < 1024; off <<= 1) {
        int t = (threadIdx.x >= (unsigned)off) ? buf[threadIdx.x - off] : 0;
        __syncthreads();
        buf[threadIdx.x] += t;
        __syncthreads();
    }
    if (i < N_NODES) rowp[i] = buf[threadIdx.x] - v;   // local exclusive
    if (threadIdx.x == 1023) part[blockIdx.x] = buf[1023];
}

__global__ void scan2(int* __restrict__ part) {        // 1 block, 64 threads
    int v = (threadIdx.x < SCAN_BLOCKS) ? part[threadIdx.x] : 0;
    for (int off = 1; off < 64; off <<= 1) {
        int t = __shfl_up(v, off);
        if ((int)threadIdx.x >= off) v += t;
    }
    if (threadIdx.x < SCAN_BLOCKS) part[threadIdx.x] = v;   // inclusive totals
}

__global__ __launch_bounds__(1024) void scan3(int* __restrict__ rowp,
                                              int* __restrict__ cursor,
                                              const int* __restrict__ part) {
    int i = blockIdx.x * 1024 + threadIdx.x;
    int off = (blockIdx.x > 0) ? part[blockIdx.x - 1] : 0;
    if (i < N_NODES) {
        int r = rowp[i] + off;
        rowp[i] = r;
        cursor[i] = r;
    }
    if (i == N_NODES) rowp[N_NODES] = part[SCAN_BLOCKS - 1];  // == N_EDGES
}

// single-pass scatter: int2{src, w} to dst-sorted position
__global__ __launch_bounds__(256) void scatter_kernel(const int* __restrict__ src,
                                                      const int* __restrict__ dst,
                                                      const float* __restrict__ ew,
                                                      int* __restrict__ cursor,
                                                      int2* __restrict__ ep) {
    int e = blockIdx.x * 256 + threadIdx.x;
    if (e < N_EDGES) {
        int d = dst[e];
        int pos = atomicAdd(&cursor[d], 1);
        int2 p; p.x = src[e]; p.y = __float_as_int(ew[e]);
        ep[pos] = p;
    }
}

// ---------------- fused SpMM + residual mix (wave-per-node, ILP-4) ----------
// One 64-lane wave per node: lane = (edge-group eg 0..3, feature-octet 0..15).
// Loop steps 16 edges: each lane holds 4 INDEPENDENT (ep, row-gather) pairs in
// flight (spmm6 had only 1 -> serial latency chain; that was the R8 regression).
// Mean degree 16 -> typical node is exactly one iteration.

__global__ __launch_bounds__(256) void spmm7(const unsigned short* __restrict__ hB,
                                             const unsigned short* __restrict__ x0B,
                                             const int* __restrict__ rowp,
                                             const int2* __restrict__ ep,
                                             unsigned short* __restrict__ mB) {
    int node = blockIdx.x * 4 + (threadIdx.x >> 6);   // 4 waves/block
    int lane = threadIdx.x & 63;
    int eg = lane >> 4;                               // edge group 0..3
    int fb = (lane & 15) * 8;                         // feature octet
    int beg = rowp[node], end = rowp[node + 1];
    float acc[8] = {0.f, 0.f, 0.f, 0.f, 0.f, 0.f, 0.f, 0.f};
    if (beg < end) {
        int last = end - 1;
        for (int i = beg; i < end; i += 16) {
            int i0 = i + eg, i1 = i0 + 4, i2 = i0 + 8, i3 = i0 + 12;
            int2 e0 = ep[min(i0, last)];
            int2 e1 = ep[min(i1, last)];
            int2 e2 = ep[min(i2, last)];
            int2 e3 = ep[min(i3, last)];
            short8 r0 = *(const short8*)(const void*)(hB + (size_t)e0.x * DIM + fb);
            short8 r1 = *(const short8*)(const void*)(hB + (size_t)e1.x * DIM + fb);
            short8 r2 = *(const short8*)(const void*)(hB + (size_t)e2.x * DIM + fb);
            short8 r3 = *(const short8*)(const void*)(hB + (size_t)e3.x * DIM + fb);
            float w0 = (i0 < end) ? __int_as_float(e0.y) : 0.f;
            float w1 = (i1 < end) ? __int_as_float(e1.y) : 0.f;
            float w2 = (i2 < end) ? __int_as_float(e2.y) : 0.f;
            float w3 = (i3 < end) ? __int_as_float(e3.y) : 0.f;
#pragma unroll
            for (int j = 0; j < 8; j++) {
                acc[j] = fmaf(w0, bf16_to_f32((unsigned short)r0[j]), acc[j]);
                acc[j] = fmaf(w1, bf16_to_f32((unsigned short)r1[j]), acc[j]);
                acc[j] = fmaf(w2, bf16_to_f32((unsigned short)r2[j]), acc[j]);
                acc[j] = fmaf(w3, bf16_to_f32((unsigned short)r3[j]), acc[j]);
            }
        }
    }
    // reduce the 4 edge groups into lanes 0..15
#pragma unroll
    for (int j = 0; j < 8; j++) {
        acc[j] += __shfl_down(acc[j], 32);
        acc[j] += __shfl_down(acc[j], 16);
    }
    if (lane < 16) {
        size_t off = (size_t)node * DIM + fb;
        short8 xv = *(const short8*)(const void*)(x0B + off);
        short8 o;
#pragma unroll
        for (int j = 0; j < 8; j++)
            o[j] = (short)f32_to_bf16(0.9f * acc[j]
                                      + 0.1f * bf16_to_f32((unsigned short)xv[j]));
        *(short8*)(void*)(mB + off) = o;
    }
}

// ---------------- MFMA GEMM: out = relu(A @ (cg*W + cm*I) + bias) -----------
// Residual FOLDED into the weight during LDS staging: W'[k][n] = cg*W + cm*I.
// A: [N,128] row-major, f32 (AF32=true) or bf16. outF f32 / outB bf16 optional.

template <bool AF32>
__global__ __launch_bounds__(256) void gemm128(const void* __restrict__ Av,
                                               const float* __restrict__ W,
                                               const float* __restrict__ bias,
                                               float* __restrict__ outF,
                                               unsigned short* __restrict__ outB,
                                               float cm, float cg) {
    __shared__ unsigned short WT[128][136];   // transposed, +8 pad
    for (int idx = threadIdx.x; idx < 128 * 128; idx += 256) {
        int k = idx >> 7, n = idx & 127;
        float wv = cg * W[idx] + ((n == k) ? cm : 0.f);
        WT[n][k] = f32_to_bf16(wv);
    }
    __syncthreads();

    int wave = threadIdx.x >> 6;
    int lane = threadIdx.x & 63;
    int r0 = (blockIdx.x * 4 + wave) * 16;
    if (r0 >= N_NODES) return;                 // 16 | 50000, full tiles only

    int mrow = lane & 15;                      // A row within tile; also C col
    int quad = lane >> 4;

    floatx4 acc[8];
#pragma unroll
    for (int t = 0; t < 8; t++) acc[t] = {0.f, 0.f, 0.f, 0.f};

#pragma unroll
    for (int k0 = 0; k0 < 128; k0 += 32) {
        short8 a;
        if constexpr (AF32) {
            const float* arow = (const float*)Av + (size_t)(r0 + mrow) * DIM;
            floatx4 alo = *(const floatx4*)(const void*)(arow + k0 + quad * 8);
            floatx4 ahi = *(const floatx4*)(const void*)(arow + k0 + quad * 8 + 4);
#pragma unroll
            for (int j = 0; j < 4; j++) a[j] = (short)f32_to_bf16(alo[j]);
#pragma unroll
            for (int j = 0; j < 4; j++) a[4 + j] = (short)f32_to_bf16(ahi[j]);
        } else {
            const unsigned short* arow = (const unsigned short*)Av + (size_t)(r0 + mrow) * DIM;
            a = *(const short8*)(const void*)(arow + k0 + quad * 8);
        }
#pragma unroll
        for (int t = 0; t < 8; t++) {
            short8 b = *(const short8*)(const void*)(&WT[t * 16 + mrow][k0 + quad * 8]);
            acc[t] = __builtin_amdgcn_mfma_f32_16x16x32_bf16(a, b, acc[t], 0, 0, 0);
        }
    }

    // C/D layout: col = lane&15, row = quad*4 + i  [verified m89/m91]
#pragma unroll
    for (int t = 0; t < 8; t++) {
        int col = t * 16 + mrow;
        float bv = bias ? bias[col] : 0.f;
#pragma unroll
        for (int i = 0; i < 4; i++) {
            int row = r0 + quad * 4 + i;
            size_t off = (size_t)row * DIM + col;
            float v = fmaxf(acc[t][i] + bv, 0.f);
            if (outF) outF[off] = v;
            if (outB) outB[off] = f32_to_bf16(v);
        }
    }
}

// ---------------- launch ----------------

extern "C" void kernel_launch(void* const* d_in, const int* in_sizes, int n_in,
                              void* d_out, int out_size, void* d_ws, size_t ws_size,
                              hipStream_t stream) {
    const float* x    = (const float*)d_in[0];
    const float* ew   = (const float*)d_in[1];
    const float* Wlin = (const float*)d_in[2];
    const float* blin = (const float*)d_in[3];
    const float* Wcv  = (const float*)d_in[4];
    const int* eidx = (const int*)d_in[5];
    const int* esrc = eidx;
    const int* edst = eidx + N_EDGES;
    float* out = (float*)d_out;

    char* ws = (char*)d_ws;
    unsigned short* x0B = (unsigned short*)(ws);             // 12.8 MB bf16 x0 rows
    unsigned short* mB  = (unsigned short*)(ws + 12800000);  // 12.8 MB bf16 m rows
    unsigned short* hB  = (unsigned short*)(ws + 25600000);  // 12.8 MB bf16 h rows
    int* rowp           = (int*)(ws + 38400000);             // (N+1)*4
    int* cursor         = (int*)(ws + 38600064);             // also 'deg'
    int2* epack         = (int2*)(ws + 38800128);            // E*8
    int* part           = (int*)(ws + 45200128);             // scan partials
    // total ~45.2 MB

    // CSR build (every call; no static state)
    (void)hipMemsetAsync(cursor, 0, (N_NODES + 1) * sizeof(int), stream);
    hist_kernel<<<(N_EDGES + 255) / 256, 256, 0, stream>>>(edst, cursor);
    scan1<<<SCAN_BLOCKS, 1024, 0, stream>>>(cursor, rowp, part);
    scan2<<<1, 64, 0, stream>>>(part);
    scan3<<<SCAN_BLOCKS, 1024, 0, stream>>>(rowp, cursor, part);
    scatter_kernel<<<(N_EDGES + 255) / 256, 256, 0, stream>>>(esrc, edst, ew, cursor, epack);

    const int grid = (N_NODES + 63) / 64;   // 782

    // x0 = relu(x @ W_lin + b_lin) -> bf16 rows
    gemm128<true><<<grid, 256, 0, stream>>>(x, Wlin, blin, nullptr, x0B, 0.f, 1.f);

    const unsigned short* hin = x0B;
    for (int l = 0; l < 8; l++) {
        spmm7<<<N_NODES / 4, 256, 0, stream>>>(hin, x0B, rowp, epack, mB);
        float beta = logf(0.5f / (float)(l + 1) + 1.f);
        gemm128<false><<<grid, 256, 0, stream>>>(mB, Wcv + (size_t)l * DIM * DIM, nullptr,
                                                 (l == 7) ? out : nullptr,
                                                 (l < 7) ? hB : nullptr,
                                                 1.f - beta, beta);
        hin = hB;
    }
}